// Round 1
// baseline (140.123 us; speedup 1.0000x reference)
//
#include <hip/hip_runtime.h>
#include <math.h>

// Problem constants (from reference)
constexpr int VOCAB = 100000;
constexpr int DIM   = 128;
constexpr int B     = 16384;
constexpr int K     = 10;

__global__ void zero_out_kernel(float* __restrict__ out) {
    out[0] = 0.0f;
}

// 32 lanes per batch element; each lane loads float4 (4 dims) -> 32*4 = 128 = DIM.
// Block of 256 threads covers 8 batch elements.
__global__ __launch_bounds__(256) void skipgram_loss_kernel(
    const int*   __restrict__ center_id,
    const int*   __restrict__ pos_id,
    const int*   __restrict__ neg_ids,
    const float* __restrict__ W_in,
    const float* __restrict__ W_out,
    float*       __restrict__ out)
{
    const int tid    = threadIdx.x;
    const int lane32 = tid & 31;   // dim-group index (0..31)
    const int sub    = tid >> 5;   // batch element within block (0..7)
    const int b      = blockIdx.x * 8 + sub;

    const int cid = center_id[b];
    const int pid = pos_id[b];

    const float4* crow = (const float4*)(W_in  + (size_t)cid * DIM);
    const float4* prow = (const float4*)(W_out + (size_t)pid * DIM);

    float4 c = crow[lane32];
    float4 p = prow[lane32];

    // Sum the 10 negative rows first: neg contribution is
    // log_sigmoid(-dot(center, sum_k neg_k))  (sum over k happens before sigmoid)
    float4 ns = make_float4(0.f, 0.f, 0.f, 0.f);
#pragma unroll
    for (int k = 0; k < K; ++k) {
        const int nid = neg_ids[b * K + k];
        const float4 n = ((const float4*)(W_out + (size_t)nid * DIM))[lane32];
        ns.x += n.x; ns.y += n.y; ns.z += n.z; ns.w += n.w;
    }

    float pos_partial = c.x * p.x  + c.y * p.y  + c.z * p.z  + c.w * p.w;
    float neg_partial = c.x * ns.x + c.y * ns.y + c.z * ns.z + c.w * ns.w;

    // Reduce across the 32 lanes that share this batch element.
    // xor masks <= 16 stay within each 32-lane half of the 64-lane wave.
#pragma unroll
    for (int m = 16; m >= 1; m >>= 1) {
        pos_partial += __shfl_xor(pos_partial, m, 64);
        neg_partial += __shfl_xor(neg_partial, m, 64);
    }

    __shared__ float blocksum[8];
    if (lane32 == 0) {
        const float ps = pos_partial;
        const float nsc = neg_partial;
        // stable log_sigmoid(x) = min(x,0) - log1p(exp(-|x|))
        const float lp = fminf(ps,   0.f) - log1pf(expf(-fabsf(ps)));
        const float ln = fminf(-nsc, 0.f) - log1pf(expf(-fabsf(nsc)));
        blocksum[sub] = lp + ln;
    }
    __syncthreads();

    if (tid == 0) {
        float s = 0.f;
#pragma unroll
        for (int i = 0; i < 8; ++i) s += blocksum[i];
        atomicAdd(out, -s);   // loss = -(sum of log-sigmoids)
    }
}

extern "C" void kernel_launch(void* const* d_in, const int* in_sizes, int n_in,
                              void* d_out, int out_size, void* d_ws, size_t ws_size,
                              hipStream_t stream) {
    const int*   center_id = (const int*)  d_in[0];
    const int*   pos_id    = (const int*)  d_in[1];
    const int*   neg_ids   = (const int*)  d_in[2];
    const float* W_in      = (const float*)d_in[3];
    const float* W_out     = (const float*)d_in[4];
    float*       out       = (float*)d_out;

    zero_out_kernel<<<1, 1, 0, stream>>>(out);

    const int b_per_block = 8;
    const int grid = B / b_per_block;   // 16384 / 8 = 2048
    skipgram_loss_kernel<<<grid, 256, 0, stream>>>(
        center_id, pos_id, neg_ids, W_in, W_out, out);
}